// Round 10
// baseline (584.657 us; speedup 1.0000x reference)
//
#include <hip/hip_runtime.h>
#include <stdint.h>

#define B_ 16
#define S_ 64
#define M_ 4096
#define D_ 1024
#define H_ 16
#define DH_ 64

typedef unsigned short ushort_t;
typedef __attribute__((ext_vector_type(8))) __bf16 bfrag;    // 8 bf16 = 4 VGPRs
typedef __attribute__((ext_vector_type(4))) float f32x4;
typedef __attribute__((ext_vector_type(16))) float f32x16;

// fp32 -> bf16 RNE
__device__ __forceinline__ ushort_t f2bf(float f) {
  union { float f; uint32_t u; } v; v.f = f;
  uint32_t r = v.u + 0x7fffu + ((v.u >> 16) & 1u);
  return (ushort_t)(r >> 16);
}

__device__ __forceinline__ void gload_lds16(const void* g, void* l) {
  __builtin_amdgcn_global_load_lds((const __attribute__((address_space(1))) void*)g,
                                   (__attribute__((address_space(3))) void*)l, 16, 0, 0);
}

__device__ __forceinline__ f32x4 mfma16(bfrag a, bfrag b, f32x4 c) {
  return __builtin_amdgcn_mfma_f32_16x16x32_bf16(a, b, c, 0, 0, 0);
}
__device__ __forceinline__ f32x16 mfma32(bfrag a, bfrag b, f32x16 c) {
  return __builtin_amdgcn_mfma_f32_32x32x16_bf16(a, b, c, 0, 0, 0);
}

// ---------------- LayerNorm rows (1024 wide) -> bf16 ----------------
__global__ __launch_bounds__(256) void ln_rows_kernel(
    const float* __restrict__ x, const float* __restrict__ g,
    const float* __restrict__ bta, ushort_t* __restrict__ out) {
  const int row = blockIdx.x;
  const int t = threadIdx.x;
  const float4* xr = (const float4*)(x + (size_t)row * D_);
  float4 v = xr[t];
  float s = v.x + v.y + v.z + v.w;
  float ss = v.x * v.x + v.y * v.y + v.z * v.z + v.w * v.w;
#pragma unroll
  for (int o = 32; o >= 1; o >>= 1) { s += __shfl_down(s, o); ss += __shfl_down(ss, o); }
  __shared__ float red[16];
  const int wid = t >> 6;
  if ((t & 63) == 0) { red[wid] = s; red[8 + wid] = ss; }
  __syncthreads();
  float tot = red[0] + red[1] + red[2] + red[3];
  float tot2 = red[8] + red[9] + red[10] + red[11];
  float mu = tot * (1.0f / D_);
  float var = tot2 * (1.0f / D_) - mu * mu;
  float rstd = rsqrtf(var + 1e-5f);
  float4 gg = ((const float4*)g)[t];
  float4 bb = ((const float4*)bta)[t];
  ushort_t ob[4];
  ob[0] = f2bf((v.x - mu) * rstd * gg.x + bb.x);
  ob[1] = f2bf((v.y - mu) * rstd * gg.y + bb.y);
  ob[2] = f2bf((v.z - mu) * rstd * gg.z + bb.z);
  ob[3] = f2bf((v.w - mu) * rstd * gg.w + bb.w);
  *(uint2*)(out + (size_t)row * D_ + t * 4) = *(const uint2*)ob;
}

// ---------------- W[K=1024][N] fp32 -> WT[N][1024] bf16 (scaled) ----------------
__global__ void transpose_cast_kernel(const float* __restrict__ W, ushort_t* __restrict__ WT,
                                      int N, float scale) {
  __shared__ float tile[32][33];
  const int n0 = blockIdx.x * 32, k0 = blockIdx.y * 32;
  const int tx = threadIdx.x, ty = threadIdx.y;
#pragma unroll
  for (int i = ty; i < 32; i += 8)
    tile[i][tx] = W[(size_t)(k0 + i) * N + n0 + tx];
  __syncthreads();
#pragma unroll
  for (int i = ty; i < 32; i += 8)
    WT[(size_t)(n0 + i) * D_ + k0 + tx] = f2bf(tile[tx][i] * scale);
}

// ---------------- kv GEMM (small, 4.3 GF): 128x128, scatter to (b,h,s,d) ----------
__global__ __launch_bounds__(256) void gemm_kv_kernel(
    const ushort_t* __restrict__ A, const ushort_t* __restrict__ Bt,
    ushort_t* __restrict__ kb, ushort_t* __restrict__ vb) {
  __shared__ __align__(16) ushort_t sA[128 * 32];
  __shared__ __align__(16) ushort_t sB[128 * 32];
  const int tid = threadIdx.x, wid = tid >> 6, lane = tid & 63;
  const size_t arow0 = (size_t)blockIdx.x * 128;
  const size_t brow0 = (size_t)blockIdx.y * 128;
  const int wr = (wid >> 1) * 64, wc = (wid & 1) * 64;
  const int srow = tid >> 2, scol = (tid & 3) * 8;
  const ushort_t* ga = A + (arow0 + srow) * (size_t)D_ + scol;
  const ushort_t* gb = Bt + (brow0 + srow) * (size_t)D_ + scol;
  const int frow = lane & 15, kslot = (lane >> 4) * 8;
  f32x4 acc[4][4] = {};
  for (int k0 = 0; k0 < D_; k0 += 32) {
    gload_lds16(ga, sA + wid * 512);
    gload_lds16(ga + 64 * (size_t)D_, sA + 2048 + wid * 512);
    gload_lds16(gb, sB + wid * 512);
    gload_lds16(gb + 64 * (size_t)D_, sB + 2048 + wid * 512);
    ga += 32; gb += 32;
    __syncthreads();
    bfrag af[4], bfv[4];
#pragma unroll
    for (int m = 0; m < 4; ++m)
      af[m] = *(const bfrag*)&sA[(wr + m * 16 + frow) * 32 + kslot];
#pragma unroll
    for (int n = 0; n < 4; ++n)
      bfv[n] = *(const bfrag*)&sB[(wc + n * 16 + frow) * 32 + kslot];
#pragma unroll
    for (int m = 0; m < 4; ++m)
#pragma unroll
      for (int n = 0; n < 4; ++n)
        acc[m][n] = mfma16(af[m], bfv[n], acc[m][n]);
    __syncthreads();
  }
  const int erow = (lane >> 4) * 4, ecol = lane & 15;
#pragma unroll
  for (int m = 0; m < 4; ++m)
#pragma unroll
    for (int n = 0; n < 4; ++n)
#pragma unroll
      for (int r = 0; r < 4; ++r) {
        size_t i = arow0 + wr + m * 16 + erow + r;
        int bb = (int)(i >> 6), s = (int)(i & 63);
        size_t n2 = brow0 + wc + n * 16 + ecol;
        ushort_t val = f2bf(acc[m][n][r]);
        ushort_t* dst = (n2 < 1024) ? kb : vb;
        size_t hh = (n2 & 1023) >> 6, d = n2 & 63;
        dst[(((size_t)bb * H_ + hh) * S_ + s) * DH_ + d] = val;
      }
}

// ============== FAT-WAVE 256x256 GEMM: 4 waves, 128x128/wave, 32x32x16 MFMA =======
// R3-R9: 8 schedules all hit ~660TF because per-wave tile 128x64 fixes LDS frag
// traffic at ~96KB/CU/ghalf vs 1242cyc MFMA — pipe-ratio bound, not schedule.
// Fix the RATIO: per-wave output 128x128 (acc 16x f32x16 = 256 VGPR, 1 wave/SIMD)
// halves LDS reads/FLOP (16 b128/wave/ghalf). 4-wave block, 3-slot LDS ring
// (32KB/slot = 96KB), vmcnt(8) counted (8 gloads/stage, 2 ahead), ONE barrier
// per ghalf. A single wave's 32-MFMA cluster (~1000cyc) self-hides reads.
// Frag layout (32x32x16): A/B lane reads row/col = lane&31, k = (lane>>5)*8,
// C: col = lane&31, row = (r&3)+8*(r>>2)+4*(lane>>5)  [m74/m101].
// LDS granule swizzle ^((row>>1)&3): 2-way/quarter-wave = free (m136); matches
// staging pre-swizzle gsrc = (tid&3)^((tid>>3)&3) (m173 pattern).
// MODE 0: fp32 C store; MODE 1: fused attention, 2 heads x 2 row-halves per wave.
template <int MODE>
__global__ __launch_bounds__(256, 1) void gemm_fat_kernel(
    const ushort_t* __restrict__ A, const ushort_t* __restrict__ Bt,
    const ushort_t* __restrict__ kbuf, const ushort_t* __restrict__ vbuf,
    void* __restrict__ Cout) {
  __shared__ __align__(16) ushort_t lds[49152];  // 96KB: 3 slots x (A 16KB | B 16KB)
  const int tid = threadIdx.x, wid = tid >> 6, lane = tid & 63;
  const int l31 = lane & 31, l5 = lane >> 5;
  const int frow = lane & 15, klo = lane >> 4;
  const int wm = wid >> 1, wn = wid & 1;

  // chunked XCD map: 1024 = 8 x 128; consecutive l share mblk (A-panel L2 reuse)
  const int l = ((int)blockIdx.x & 7) * 128 + ((int)blockIdx.x >> 3);
  const int mblk = l >> 2, nblk = l & 3;
  const size_t arow0 = (size_t)mblk * 256;
  const size_t bcol0 = (size_t)nblk * 256;

  // staging: thread covers rows r0 + j*64, stored granule tid&3 holds source
  // granule (tid&3)^((row>>1)&3); LDS dst linear = wave base + lane*16B
  const int r0 = tid >> 2;
  const int gsrc = (tid & 3) ^ ((tid >> 3) & 3);
  const ushort_t* pA = A + (arow0 + r0) * (size_t)D_ + gsrc * 8;
  const ushort_t* pB = Bt + (bcol0 + r0) * (size_t)D_ + gsrc * 8;

#define STAGE(G, SLOT)                                                          \
  do {                                                                          \
    const size_t ko_ = (size_t)((G) < 32 ? (G) : 31) * 32;                      \
    _Pragma("unroll") for (int j = 0; j < 4; ++j)                               \
        gload_lds16(pA + (size_t)j * 64 * D_ + ko_,                             \
                    &lds[(SLOT) * 16384 + j * 2048 + wid * 512]);               \
    _Pragma("unroll") for (int j = 0; j < 4; ++j)                               \
        gload_lds16(pB + (size_t)j * 64 * D_ + ko_,                             \
                    &lds[(SLOT) * 16384 + 8192 + j * 2048 + wid * 512]);        \
  } while (0)

  // prologue: ghalfs 0,1 (16 gloads/thread outstanding)
  STAGE(0, 0);
  STAGE(1, 1);

  // per-lane read constants: row = base + l31; swizzle sw3 = ((row>>1)&3)
  const int sw3 = (l31 >> 1) & 3;
  const int aBase = wm * 4096 + l31 * 32;          // + slot*16384 + mf*1024 + g*8
  const int bBase = 8192 + wn * 4096 + l31 * 32;   // + slot*16384 + nf*1024 + g*8

  f32x16 acc[4][4] = {};
  int sl = 0;  // slot of ghalf g
  for (int g = 0; g < 32; ++g) {
    asm volatile("s_waitcnt vmcnt(8)" ::: "memory");  // ghalf g landed (g+1 in flight)
    __builtin_amdgcn_s_barrier();
    asm volatile("" ::: "memory");
    const int snext = (sl + 2 >= 3) ? sl - 1 : sl + 2;  // (g+2)%3
    STAGE(g + 2, snext);
    const int sb = sl * 16384;
    bfrag af[4][2], bf[4][2];
#pragma unroll
    for (int kk = 0; kk < 2; ++kk) {
      const int gk = (((kk << 1) | l5) ^ sw3) * 8;
#pragma unroll
      for (int mf = 0; mf < 4; ++mf)
        af[mf][kk] = *(const bfrag*)&lds[sb + aBase + mf * 1024 + gk];
#pragma unroll
      for (int nf = 0; nf < 4; ++nf)
        bf[nf][kk] = *(const bfrag*)&lds[sb + bBase + nf * 1024 + gk];
    }
#pragma unroll
    for (int kk = 0; kk < 2; ++kk)
#pragma unroll
      for (int mf = 0; mf < 4; ++mf)
#pragma unroll
        for (int nf = 0; nf < 4; ++nf)
          acc[mf][nf] = mfma32(af[mf][kk], bf[nf][kk], acc[mf][nf]);
    sl = (sl + 1 >= 3) ? 0 : sl + 1;
  }
  // drain tail garbage-stages before reusing LDS / exiting
  asm volatile("s_waitcnt vmcnt(0)" ::: "memory");
  __builtin_amdgcn_s_barrier();
  asm volatile("" ::: "memory");
#undef STAGE

  if constexpr (MODE == 0) {
    // ---------- epilogue: fp32 C store (32x32 C layout) ----------
    float* C = (float*)Cout;
#pragma unroll
    for (int m2 = 0; m2 < 4; ++m2)
#pragma unroll
      for (int n2 = 0; n2 < 4; ++n2)
#pragma unroll
        for (int r = 0; r < 16; ++r) {
          const int row = m2 * 32 + (r & 3) + 8 * (r >> 2) + 4 * l5;
          C[(arow0 + wm * 128 + row) * 1024 + bcol0 + wn * 128 + n2 * 32 + l31] =
              acc[m2][n2][r];
        }
  } else {
    // ---------- epilogue: fused attention, 4 passes (2 row-halves x 2 heads) -----
    ushort_t* W = &lds[wid * 4096];  // per-wave [64][64] bf16, granule ^= row&7
    ushort_t* out1 = (ushort_t*)Cout;
    const int bbatch = mblk >> 4;
#pragma unroll
    for (int rh = 0; rh < 2; ++rh)
#pragma unroll
      for (int h2 = 0; h2 < 2; ++h2) {
        const int head = nblk * 4 + wn * 2 + h2;
        const size_t kvbase = ((size_t)bbatch * H_ + head) * (size_t)(S_ * DH_);
        // q -> W (from 32x32 acc frags; W row64/col64 in [0,64))
#pragma unroll
        for (int m2i = 0; m2i < 2; ++m2i)
#pragma unroll
          for (int n2i = 0; n2i < 2; ++n2i)
#pragma unroll
            for (int r = 0; r < 16; ++r) {
              const int row = m2i * 32 + (r & 3) + 8 * (r >> 2) + 4 * l5;
              const int col = n2i * 32 + l31;
              W[row * 64 + ((((col >> 3) ^ (row & 7)) << 3) | (col & 7))] =
                  f2bf(acc[rh * 2 + m2i][h2 * 2 + n2i][r]);
            }
        // sim = q @ K^T (16x16x32 MFMA; q rows from W)
        bfrag kb[4][2];
#pragma unroll
        for (int nf = 0; nf < 4; ++nf)
#pragma unroll
          for (int kk = 0; kk < 2; ++kk)
            kb[nf][kk] = *(const bfrag*)&kbuf[kvbase + (nf * 16 + frow) * 64 +
                                              kk * 32 + klo * 8];
        f32x4 s[4][4] = {};
#pragma unroll
        for (int mm = 0; mm < 4; ++mm) {
          const int row = mm * 16 + frow;
#pragma unroll
          for (int kk = 0; kk < 2; ++kk) {
            bfrag qa = *(const bfrag*)&W[row * 64 + (((kk * 4 + klo) ^ (frow & 7)) << 3)];
#pragma unroll
            for (int nf = 0; nf < 4; ++nf)
              s[mm][nf] = mfma16(qa, kb[nf][kk], s[mm][nf]);
          }
        }
        // softmax over 64 keys (row = 16-lane group x 4 regs)
#pragma unroll
        for (int mm = 0; mm < 4; ++mm)
#pragma unroll
          for (int r = 0; r < 4; ++r) {
            float a0 = s[mm][0][r], a1 = s[mm][1][r], a2 = s[mm][2][r], a3 = s[mm][3][r];
            float mx = fmaxf(fmaxf(a0, a1), fmaxf(a2, a3));
#pragma unroll
            for (int o = 1; o < 16; o <<= 1) mx = fmaxf(mx, __shfl_xor(mx, o));
            a0 = __expf(a0 - mx); a1 = __expf(a1 - mx);
            a2 = __expf(a2 - mx); a3 = __expf(a3 - mx);
            float sm = (a0 + a1) + (a2 + a3);
#pragma unroll
            for (int o = 1; o < 16; o <<= 1) sm += __shfl_xor(sm, o);
            const float inv = 1.0f / sm;
            s[mm][0][r] = a0 * inv; s[mm][1][r] = a1 * inv;
            s[mm][2][r] = a2 * inv; s[mm][3][r] = a3 * inv;
          }
        // P -> W (overwrite q; wave-private)
#pragma unroll
        for (int mm = 0; mm < 4; ++mm)
#pragma unroll
          for (int r = 0; r < 4; ++r) {
            const int row = mm * 16 + klo * 4 + r;
#pragma unroll
            for (int nf = 0; nf < 4; ++nf) {
              const int col = nf * 16 + frow;
              W[row * 64 + ((((col >> 3) ^ (row & 7)) << 3) | (col & 7))] =
                  f2bf(s[mm][nf][r]);
            }
          }
        // out_half = attn @ "V^T" (source einsum quirk)
        bfrag vb[4][2];
#pragma unroll
        for (int nf = 0; nf < 4; ++nf)
#pragma unroll
          for (int kk = 0; kk < 2; ++kk)
            vb[nf][kk] = *(const bfrag*)&vbuf[kvbase + (nf * 16 + frow) * 64 +
                                              kk * 32 + klo * 8];
        f32x4 o[4][4] = {};
#pragma unroll
        for (int mm = 0; mm < 4; ++mm) {
          const int row = mm * 16 + frow;
#pragma unroll
          for (int kk = 0; kk < 2; ++kk) {
            bfrag pa = *(const bfrag*)&W[row * 64 + (((kk * 4 + klo) ^ (frow & 7)) << 3)];
#pragma unroll
            for (int nf = 0; nf < 4; ++nf)
              o[mm][nf] = mfma16(pa, vb[nf][kk], o[mm][nf]);
          }
        }
        // o -> W, then coalesced uint4 stores
#pragma unroll
        for (int mm = 0; mm < 4; ++mm)
#pragma unroll
          for (int r = 0; r < 4; ++r) {
            const int row = mm * 16 + klo * 4 + r;
#pragma unroll
            for (int nf = 0; nf < 4; ++nf) {
              const int col = nf * 16 + frow;
              W[row * 64 + ((((col >> 3) ^ (row & 7)) << 3) | (col & 7))] =
                  f2bf(o[mm][nf][r]);
            }
          }
        const size_t grow0 = arow0 + wm * 128 + rh * 64;
#pragma unroll
        for (int it = 0; it < 8; ++it) {
          const int idx = it * 64 + lane;
          const int rr = idx >> 3, gs = idx & 7;
          const int gcol = (gs ^ (rr & 7)) << 3;
          *(uint4*)&out1[(grow0 + rr) * 1024 + head * 64 + gcol] =
              *(const uint4*)&W[rr * 64 + gs * 8];
        }
      }
  }
}

// -------------------------------- launch --------------------------------
extern "C" void kernel_launch(void* const* d_in, const int* in_sizes, int n_in,
                              void* d_out, int out_size, void* d_ws, size_t ws_size,
                              hipStream_t stream) {
  const float* x = (const float*)d_in[0];
  const float* lat = (const float*)d_in[1];
  const float* lxg = (const float*)d_in[2];
  const float* lxb = (const float*)d_in[3];
  const float* llg = (const float*)d_in[4];
  const float* llb = (const float*)d_in[5];
  const float* Wq = (const float*)d_in[6];
  const float* Wkv = (const float*)d_in[7];
  const float* Wout = (const float*)d_in[8];
  float* out = (float*)d_out;
  char* ws = (char*)d_ws;

  // ws layout (142MB): xn 2MB | wqT 2MB | wkvT 4MB | woT 2MB | k 2MB | v 2MB | out1 128MB
  ushort_t* xn = (ushort_t*)(ws);
  ushort_t* wqT = (ushort_t*)(ws + (2ull << 20));
  ushort_t* wkvT = (ushort_t*)(ws + (4ull << 20));
  ushort_t* woT = (ushort_t*)(ws + (8ull << 20));
  ushort_t* kbuf = (ushort_t*)(ws + (10ull << 20));
  ushort_t* vbuf = (ushort_t*)(ws + (12ull << 20));
  ushort_t* out1 = (ushort_t*)(ws + (14ull << 20));
  // lnl (bf16, 128MB) lives in d_out's first half: dead before final GEMM writes d_out
  ushort_t* lnl = (ushort_t*)d_out;

  dim3 tb(32, 8);
  transpose_cast_kernel<<<dim3(1024 / 32, 32), tb, 0, stream>>>(Wq, wqT, 1024, 0.125f);
  transpose_cast_kernel<<<dim3(2048 / 32, 32), tb, 0, stream>>>(Wkv, wkvT, 2048, 1.0f);
  transpose_cast_kernel<<<dim3(1024 / 32, 32), tb, 0, stream>>>(Wout, woT, 1024, 1.0f);
  ln_rows_kernel<<<B_ * S_, 256, 0, stream>>>(x, lxg, lxb, xn);
  ln_rows_kernel<<<B_ * M_, 256, 0, stream>>>(lat, llg, llb, lnl);
  gemm_kv_kernel<<<dim3(8, 16), 256, 0, stream>>>(xn, wkvT, kbuf, vbuf);
  gemm_fat_kernel<1><<<1024, 256, 0, stream>>>(lnl, wqT, kbuf, vbuf, out1);
  gemm_fat_kernel<0><<<1024, 256, 0, stream>>>(out1, woT, nullptr, nullptr, out);
}